// Round 1
// baseline (679.132 us; speedup 1.0000x reference)
//
#include <hip/hip_runtime.h>
#include <hip/hip_bf16.h>
#include <math.h>

#define D 128

__device__ __forceinline__ float wave_sum(float v) {
#pragma unroll
  for (int off = 32; off; off >>= 1) v += __shfl_xor(v, off, 64);
  return v;
}

// ---------------- Kernel A: intra-path attention (one wave per node) ----------------
template<int S>
__global__ __launch_bounds__(256) void k_intra(
    const float* __restrict__ h_ref, const float* __restrict__ h,
    const int* __restrict__ nei, const float* __restrict__ att,
    float* __restrict__ e_out, int N)
{
  const int wid  = threadIdx.x >> 6;
  const int lane = threadIdx.x & 63;
  const int n = blockIdx.x * 4 + wid;
  if (n >= N) return;

  const float2 aref = *(const float2*)(att + 2 * lane);
  const float2 anei = *(const float2*)(att + D + 2 * lane);
  const float2 hr   = *(const float2*)(h_ref + (size_t)n * D + 2 * lane);
  const float s_ref = wave_sum(hr.x * aref.x + hr.y * aref.y);

  const int* nrow = nei + (size_t)n * S;
  float2 nb[S];
  float  sc[S];
#pragma unroll
  for (int s = 0; s < S; ++s) {
    const int idx = nrow[s];
    nb[s] = *(const float2*)(h + (size_t)idx * D + 2 * lane);
  }
#pragma unroll
  for (int s = 0; s < S; ++s)
    sc[s] = wave_sum(nb[s].x * anei.x + nb[s].y * anei.y);

  // leaky_relu + softmax over S (values uniform across lanes)
  float m = -1e30f;
#pragma unroll
  for (int s = 0; s < S; ++s) {
    float x = s_ref + sc[s];
    x = x > 0.f ? x : 0.01f * x;
    sc[s] = x;
    m = fmaxf(m, x);
  }
  float sum = 0.f;
#pragma unroll
  for (int s = 0; s < S; ++s) { sc[s] = __expf(sc[s] - m); sum += sc[s]; }
  const float inv = 1.0f / sum;

  float ex = 0.f, ey = 0.f;
#pragma unroll
  for (int s = 0; s < S; ++s) {
    const float w = sc[s] * inv;
    ex += w * nb[s].x;
    ey += w * nb[s].y;
  }
  // ELU
  ex = ex > 0.f ? ex : expm1f(ex);
  ey = ey > 0.f ? ey : expm1f(ey);
  *(float2*)(e_out + (size_t)n * D + 2 * lane) = make_float2(ex, ey);
}

// Generic fallback (runtime S), two-pass
__global__ __launch_bounds__(256) void k_intra_gen(
    const float* __restrict__ h_ref, const float* __restrict__ h,
    const int* __restrict__ nei, const float* __restrict__ att,
    float* __restrict__ e_out, int N, int S)
{
  const int wid  = threadIdx.x >> 6;
  const int lane = threadIdx.x & 63;
  const int n = blockIdx.x * 4 + wid;
  if (n >= N) return;
  const float2 aref = *(const float2*)(att + 2 * lane);
  const float2 anei = *(const float2*)(att + D + 2 * lane);
  const float2 hr   = *(const float2*)(h_ref + (size_t)n * D + 2 * lane);
  const float s_ref = wave_sum(hr.x * aref.x + hr.y * aref.y);
  const int* nrow = nei + (size_t)n * S;
  float m = -1e30f;
  for (int s = 0; s < S; ++s) {
    float2 v = *(const float2*)(h + (size_t)nrow[s] * D + 2 * lane);
    float x = s_ref + wave_sum(v.x * anei.x + v.y * anei.y);
    x = x > 0.f ? x : 0.01f * x;
    m = fmaxf(m, x);
  }
  float sum = 0.f, ex = 0.f, ey = 0.f;
  for (int s = 0; s < S; ++s) {
    float2 v = *(const float2*)(h + (size_t)nrow[s] * D + 2 * lane);
    float x = s_ref + wave_sum(v.x * anei.x + v.y * anei.y);
    x = x > 0.f ? x : 0.01f * x;
    float w = __expf(x - m);
    sum += w; ex += w * v.x; ey += w * v.y;
  }
  const float inv = 1.0f / sum;
  ex *= inv; ey *= inv;
  ex = ex > 0.f ? ex : expm1f(ex);
  ey = ey > 0.f ? ey : expm1f(ey);
  *(float2*)(e_out + (size_t)n * D + 2 * lane) = make_float2(ex, ey);
}

// ---------------- Kernel B: tanh(e @ fcW^T + fcb), column-sum over nodes ----------------
// grid (ceil(N/256), 2); blockIdx.y = path. One thread per node, e-row in registers.
__global__ __launch_bounds__(256) void k_fc(
    const float* __restrict__ e1, const float* __restrict__ e2,
    const float* __restrict__ fcW, const float* __restrict__ fcb,
    float* __restrict__ acc_out, int N)
{
  __shared__ float4 W4[D * D / 4];  // 64 KB, [j][d4]
  const float4* gW = (const float4*)fcW;
  for (int k = threadIdx.x; k < D * D / 4; k += 256) W4[k] = gW[k];
  __syncthreads();

  const int path = blockIdx.y;
  const int n = blockIdx.x * 256 + threadIdx.x;
  const int lane = threadIdx.x & 63;
  const bool active = n < N;
  const float* e = path ? e2 : e1;

  float4 er[D / 4];
  if (active) {
    const float4* erow = (const float4*)(e + (size_t)n * D);
#pragma unroll
    for (int d4 = 0; d4 < D / 4; ++d4) er[d4] = erow[d4];
  } else {
#pragma unroll
    for (int d4 = 0; d4 < D / 4; ++d4) er[d4] = make_float4(0.f, 0.f, 0.f, 0.f);
  }

  float* accp = acc_out + path * D;
#pragma unroll 2
  for (int j = 0; j < D; ++j) {
    const float4* wj = &W4[j * (D / 4)];
    float4 a0 = make_float4(0.f, 0.f, 0.f, 0.f);
    float4 a1 = make_float4(0.f, 0.f, 0.f, 0.f);
#pragma unroll
    for (int d4 = 0; d4 < D / 4; d4 += 2) {
      const float4 w0 = wj[d4], w1 = wj[d4 + 1];
      const float4 r0 = er[d4], r1 = er[d4 + 1];
      a0.x = fmaf(r0.x, w0.x, a0.x); a0.y = fmaf(r0.y, w0.y, a0.y);
      a0.z = fmaf(r0.z, w0.z, a0.z); a0.w = fmaf(r0.w, w0.w, a0.w);
      a1.x = fmaf(r1.x, w1.x, a1.x); a1.y = fmaf(r1.y, w1.y, a1.y);
      a1.z = fmaf(r1.z, w1.z, a1.z); a1.w = fmaf(r1.w, w1.w, a1.w);
    }
    float dot = (a0.x + a0.y) + (a0.z + a0.w) + (a1.x + a1.y) + (a1.z + a1.w);
    float t = active ? tanhf(dot + fcb[j]) : 0.f;
    float s = wave_sum(t);
    if (lane == 0) atomicAdd(accp + j, s);
  }
}

// ---------------- Kernel C: beta = softmax(sps @ att_inter) ----------------
__global__ void k_beta(const float* __restrict__ acc, const float* __restrict__ att_inter,
                       float* __restrict__ beta, float invN)
{
  const int lane = threadIdx.x;  // 0..63
  float v0 = (acc[lane] * invN) * att_inter[lane] +
             (acc[lane + 64] * invN) * att_inter[lane + 64];
  float v1 = (acc[D + lane] * invN) * att_inter[lane] +
             (acc[D + lane + 64] * invN) * att_inter[lane + 64];
  v0 = wave_sum(v0);
  v1 = wave_sum(v1);
  if (lane == 0) {
    const float m = fmaxf(v0, v1);
    const float p0 = __expf(v0 - m), p1 = __expf(v1 - m);
    const float inv = 1.f / (p0 + p1);
    beta[0] = p0 * inv;
    beta[1] = p1 * inv;
  }
}

// ---------------- Kernel D: out = b0*e1 + b1*e2 ----------------
__global__ __launch_bounds__(256) void k_combine(
    const float* __restrict__ e1, const float* __restrict__ e2,
    const float* __restrict__ beta, float* __restrict__ out, int total4)
{
  const float b0 = beta[0], b1 = beta[1];
  const float4* p1 = (const float4*)e1;
  const float4* p2 = (const float4*)e2;
  float4* po = (float4*)out;
  int i = blockIdx.x * 256 + threadIdx.x;
  const int stride = gridDim.x * 256;
  for (; i < total4; i += stride) {
    const float4 a = p1[i], b = p2[i];
    po[i] = make_float4(b0 * a.x + b1 * b.x, b0 * a.y + b1 * b.y,
                        b0 * a.z + b1 * b.z, b0 * a.w + b1 * b.w);
  }
}

__global__ void k_zero(float* __restrict__ p, int n) {
  const int i = blockIdx.x * 256 + threadIdx.x;
  if (i < n) p[i] = 0.f;
}

extern "C" void kernel_launch(void* const* d_in, const int* in_sizes, int n_in,
                              void* d_out, int out_size, void* d_ws, size_t ws_size,
                              hipStream_t stream) {
  const float* h_ref     = (const float*)d_in[0];
  const float* h1        = (const float*)d_in[1];
  const float* h2        = (const float*)d_in[2];
  const int*   nei1      = (const int*)d_in[3];
  const int*   nei2      = (const int*)d_in[4];
  const float* att1      = (const float*)d_in[5];
  const float* att2      = (const float*)d_in[6];
  const float* fcW       = (const float*)d_in[7];
  const float* fcb       = (const float*)d_in[8];
  const float* att_inter = (const float*)d_in[9];

  const int N  = in_sizes[0] / D;
  const int S1 = in_sizes[3] / N;
  const int S2 = in_sizes[4] / N;

  float* e1   = (float*)d_ws;
  float* e2   = e1 + (size_t)N * D;
  float* acc  = e2 + (size_t)N * D;
  float* beta = acc + 2 * D;
  float* out  = (float*)d_out;

  k_zero<<<1, 256, 0, stream>>>(acc, 2 * D);

  const dim3 gA((N + 3) / 4);
  if (S1 == 20)      k_intra<20><<<gA, 256, 0, stream>>>(h_ref, h1, nei1, att1, e1, N);
  else if (S1 == 10) k_intra<10><<<gA, 256, 0, stream>>>(h_ref, h1, nei1, att1, e1, N);
  else               k_intra_gen<<<gA, 256, 0, stream>>>(h_ref, h1, nei1, att1, e1, N, S1);

  if (S2 == 10)      k_intra<10><<<gA, 256, 0, stream>>>(h_ref, h2, nei2, att2, e2, N);
  else if (S2 == 20) k_intra<20><<<gA, 256, 0, stream>>>(h_ref, h2, nei2, att2, e2, N);
  else               k_intra_gen<<<gA, 256, 0, stream>>>(h_ref, h2, nei2, att2, e2, N, S2);

  const dim3 gB((N + 255) / 256, 2);
  k_fc<<<gB, 256, 0, stream>>>(e1, e2, fcW, fcb, acc, N);

  k_beta<<<1, 64, 0, stream>>>(acc, att_inter, beta, 1.0f / (float)N);

  const int total4 = N * D / 4;
  int gD = (total4 + 255) / 256;
  if (gD > 2048) gD = 2048;
  k_combine<<<gD, 256, 0, stream>>>(e1, e2, beta, out, total4);
}

// Round 2
// 579.845 us; speedup vs baseline: 1.1712x; 1.1712x over previous
//
#include <hip/hip_runtime.h>
#include <hip/hip_bf16.h>
#include <math.h>

#define D 128
#define GN 16  // nodes per wave-group in k_fc2

__device__ __forceinline__ float wave_sum(float v) {
#pragma unroll
  for (int off = 32; off; off >>= 1) v += __shfl_xor(v, off, 64);
  return v;
}

__device__ __forceinline__ void fma4(const float4 w, const float4 ev, float& a) {
  a = fmaf(ev.x, w.x, a);
  a = fmaf(ev.y, w.y, a);
  a = fmaf(ev.z, w.z, a);
  a = fmaf(ev.w, w.w, a);
}

// ---------------- Kernel A: intra-path attention (one wave per node) ----------------
template<int S>
__global__ __launch_bounds__(256) void k_intra(
    const float* __restrict__ h_ref, const float* __restrict__ h,
    const int* __restrict__ nei, const float* __restrict__ att,
    float* __restrict__ e_out, int N)
{
  const int wid  = threadIdx.x >> 6;
  const int lane = threadIdx.x & 63;
  const int n = blockIdx.x * 4 + wid;
  if (n >= N) return;

  const float2 aref = *(const float2*)(att + 2 * lane);
  const float2 anei = *(const float2*)(att + D + 2 * lane);
  const float2 hr   = *(const float2*)(h_ref + (size_t)n * D + 2 * lane);
  const float s_ref = wave_sum(hr.x * aref.x + hr.y * aref.y);

  const int* nrow = nei + (size_t)n * S;
  float2 nb[S];
  float  sc[S];
#pragma unroll
  for (int s = 0; s < S; ++s) {
    const int idx = nrow[s];
    nb[s] = *(const float2*)(h + (size_t)idx * D + 2 * lane);
  }
#pragma unroll
  for (int s = 0; s < S; ++s)
    sc[s] = wave_sum(nb[s].x * anei.x + nb[s].y * anei.y);

  // leaky_relu + softmax over S (values uniform across lanes)
  float m = -1e30f;
#pragma unroll
  for (int s = 0; s < S; ++s) {
    float x = s_ref + sc[s];
    x = x > 0.f ? x : 0.01f * x;
    sc[s] = x;
    m = fmaxf(m, x);
  }
  float sum = 0.f;
#pragma unroll
  for (int s = 0; s < S; ++s) { sc[s] = __expf(sc[s] - m); sum += sc[s]; }
  const float inv = 1.0f / sum;

  float ex = 0.f, ey = 0.f;
#pragma unroll
  for (int s = 0; s < S; ++s) {
    const float w = sc[s] * inv;
    ex += w * nb[s].x;
    ey += w * nb[s].y;
  }
  // ELU
  ex = ex > 0.f ? ex : expm1f(ex);
  ey = ey > 0.f ? ey : expm1f(ey);
  *(float2*)(e_out + (size_t)n * D + 2 * lane) = make_float2(ex, ey);
}

// Generic fallback (runtime S), two-pass
__global__ __launch_bounds__(256) void k_intra_gen(
    const float* __restrict__ h_ref, const float* __restrict__ h,
    const int* __restrict__ nei, const float* __restrict__ att,
    float* __restrict__ e_out, int N, int S)
{
  const int wid  = threadIdx.x >> 6;
  const int lane = threadIdx.x & 63;
  const int n = blockIdx.x * 4 + wid;
  if (n >= N) return;
  const float2 aref = *(const float2*)(att + 2 * lane);
  const float2 anei = *(const float2*)(att + D + 2 * lane);
  const float2 hr   = *(const float2*)(h_ref + (size_t)n * D + 2 * lane);
  const float s_ref = wave_sum(hr.x * aref.x + hr.y * aref.y);
  const int* nrow = nei + (size_t)n * S;
  float m = -1e30f;
  for (int s = 0; s < S; ++s) {
    float2 v = *(const float2*)(h + (size_t)nrow[s] * D + 2 * lane);
    float x = s_ref + wave_sum(v.x * anei.x + v.y * anei.y);
    x = x > 0.f ? x : 0.01f * x;
    m = fmaxf(m, x);
  }
  float sum = 0.f, ex = 0.f, ey = 0.f;
  for (int s = 0; s < S; ++s) {
    float2 v = *(const float2*)(h + (size_t)nrow[s] * D + 2 * lane);
    float x = s_ref + wave_sum(v.x * anei.x + v.y * anei.y);
    x = x > 0.f ? x : 0.01f * x;
    float w = __expf(x - m);
    sum += w; ex += w * v.x; ey += w * v.y;
  }
  const float inv = 1.0f / sum;
  ex *= inv; ey *= inv;
  ex = ex > 0.f ? ex : expm1f(ex);
  ey = ey > 0.f ? ey : expm1f(ey);
  *(float2*)(e_out + (size_t)n * D + 2 * lane) = make_float2(ex, ey);
}

// ---------------- Kernel B (v2): tanh(e @ fcW^T + fcb), column-sum over nodes ----------
// Transposed ownership: lane owns j = {lane, lane+64}. W rows live in registers
// (reloaded per 16-wide k-chunk, L1/L2 resident). Node base index is wave-uniform
// (readfirstlane) so e-row loads become s_load. No LDS, no wave reductions.
__global__ __launch_bounds__(256) void k_fc2(
    const float* __restrict__ e1, const float* __restrict__ e2,
    const float* __restrict__ fcW, const float* __restrict__ fcb,
    float* __restrict__ acc_out, int N)
{
  const int path = blockIdx.y;
  const float* __restrict__ e = path ? e2 : e1;
  const int lane = threadIdx.x & 63;
  const int wid  = threadIdx.x >> 6;
  const int group = blockIdx.x * 4 + wid;
  const int n0 = __builtin_amdgcn_readfirstlane(group * GN);
  if (n0 >= N) return;

  const int j0 = lane;
  const int j1 = lane + 64;

  float acc0[GN], acc1[GN];
  const float b0 = fcb[j0], b1 = fcb[j1];
#pragma unroll
  for (int g = 0; g < GN; ++g) { acc0[g] = b0; acc1[g] = b1; }

  const float* __restrict__ w0p = fcW + (size_t)j0 * D;
  const float* __restrict__ w1p = fcW + (size_t)j1 * D;

#pragma unroll
  for (int c = 0; c < D / 16; ++c) {
    const float4 wa0 = *(const float4*)(w0p + c * 16 + 0);
    const float4 wa1 = *(const float4*)(w0p + c * 16 + 4);
    const float4 wa2 = *(const float4*)(w0p + c * 16 + 8);
    const float4 wa3 = *(const float4*)(w0p + c * 16 + 12);
    const float4 wb0 = *(const float4*)(w1p + c * 16 + 0);
    const float4 wb1 = *(const float4*)(w1p + c * 16 + 4);
    const float4 wb2 = *(const float4*)(w1p + c * 16 + 8);
    const float4 wb3 = *(const float4*)(w1p + c * 16 + 12);
#pragma unroll
    for (int g = 0; g < GN; ++g) {
      const int n = (n0 + g < N) ? (n0 + g) : (N - 1);  // uniform clamp, keeps loads in-bounds
      const float* __restrict__ er = e + (size_t)n * D + c * 16;
      const float4 ea = *(const float4*)(er + 0);
      const float4 eb = *(const float4*)(er + 4);
      const float4 ec = *(const float4*)(er + 8);
      const float4 ed = *(const float4*)(er + 12);
      fma4(wa0, ea, acc0[g]); fma4(wa1, eb, acc0[g]);
      fma4(wa2, ec, acc0[g]); fma4(wa3, ed, acc0[g]);
      fma4(wb0, ea, acc1[g]); fma4(wb1, eb, acc1[g]);
      fma4(wb2, ec, acc1[g]); fma4(wb3, ed, acc1[g]);
    }
  }

  float s0 = 0.f, s1 = 0.f;
#pragma unroll
  for (int g = 0; g < GN; ++g) {
    if (n0 + g < N) {
      s0 += tanhf(acc0[g]);
      s1 += tanhf(acc1[g]);
    }
  }
  float* accp = acc_out + path * D;
  atomicAdd(accp + j0, s0);
  atomicAdd(accp + j1, s1);
}

// ---------------- Kernel C: beta = softmax(sps @ att_inter) ----------------
__global__ void k_beta(const float* __restrict__ acc, const float* __restrict__ att_inter,
                       float* __restrict__ beta, float invN)
{
  const int lane = threadIdx.x;  // 0..63
  float v0 = (acc[lane] * invN) * att_inter[lane] +
             (acc[lane + 64] * invN) * att_inter[lane + 64];
  float v1 = (acc[D + lane] * invN) * att_inter[lane] +
             (acc[D + lane + 64] * invN) * att_inter[lane + 64];
  v0 = wave_sum(v0);
  v1 = wave_sum(v1);
  if (lane == 0) {
    const float m = fmaxf(v0, v1);
    const float p0 = __expf(v0 - m), p1 = __expf(v1 - m);
    const float inv = 1.f / (p0 + p1);
    beta[0] = p0 * inv;
    beta[1] = p1 * inv;
  }
}

// ---------------- Kernel D: out = b0*e1 + b1*e2 ----------------
__global__ __launch_bounds__(256) void k_combine(
    const float* __restrict__ e1, const float* __restrict__ e2,
    const float* __restrict__ beta, float* __restrict__ out, int total4)
{
  const float b0 = beta[0], b1 = beta[1];
  const float4* p1 = (const float4*)e1;
  const float4* p2 = (const float4*)e2;
  float4* po = (float4*)out;
  int i = blockIdx.x * 256 + threadIdx.x;
  const int stride = gridDim.x * 256;
  for (; i < total4; i += stride) {
    const float4 a = p1[i], b = p2[i];
    po[i] = make_float4(b0 * a.x + b1 * b.x, b0 * a.y + b1 * b.y,
                        b0 * a.z + b1 * b.z, b0 * a.w + b1 * b.w);
  }
}

__global__ void k_zero(float* __restrict__ p, int n) {
  const int i = blockIdx.x * 256 + threadIdx.x;
  if (i < n) p[i] = 0.f;
}

extern "C" void kernel_launch(void* const* d_in, const int* in_sizes, int n_in,
                              void* d_out, int out_size, void* d_ws, size_t ws_size,
                              hipStream_t stream) {
  const float* h_ref     = (const float*)d_in[0];
  const float* h1        = (const float*)d_in[1];
  const float* h2        = (const float*)d_in[2];
  const int*   nei1      = (const int*)d_in[3];
  const int*   nei2      = (const int*)d_in[4];
  const float* att1      = (const float*)d_in[5];
  const float* att2      = (const float*)d_in[6];
  const float* fcW       = (const float*)d_in[7];
  const float* fcb       = (const float*)d_in[8];
  const float* att_inter = (const float*)d_in[9];

  const int N  = in_sizes[0] / D;
  const int S1 = in_sizes[3] / N;
  const int S2 = in_sizes[4] / N;

  float* e1   = (float*)d_ws;
  float* e2   = e1 + (size_t)N * D;
  float* acc  = e2 + (size_t)N * D;
  float* beta = acc + 2 * D;
  float* out  = (float*)d_out;

  k_zero<<<1, 256, 0, stream>>>(acc, 2 * D);

  const dim3 gA((N + 3) / 4);
  if (S1 == 20)      k_intra<20><<<gA, 256, 0, stream>>>(h_ref, h1, nei1, att1, e1, N);
  else if (S1 == 10) k_intra<10><<<gA, 256, 0, stream>>>(h_ref, h1, nei1, att1, e1, N);
  else               k_intra_gen<<<gA, 256, 0, stream>>>(h_ref, h1, nei1, att1, e1, N, S1);

  if (S2 == 10)      k_intra<10><<<gA, 256, 0, stream>>>(h_ref, h2, nei2, att2, e2, N);
  else if (S2 == 20) k_intra<20><<<gA, 256, 0, stream>>>(h_ref, h2, nei2, att2, e2, N);
  else               k_intra_gen<<<gA, 256, 0, stream>>>(h_ref, h2, nei2, att2, e2, N, S2);

  const int groups = (N + GN - 1) / GN;
  const dim3 gB((groups + 3) / 4, 2);
  k_fc2<<<gB, 256, 0, stream>>>(e1, e2, fcW, fcb, acc, N);

  k_beta<<<1, 64, 0, stream>>>(acc, att_inter, beta, 1.0f / (float)N);

  const int total4 = N * D / 4;
  int gD = (total4 + 255) / 256;
  if (gD > 2048) gD = 2048;
  k_combine<<<gD, 256, 0, stream>>>(e1, e2, beta, out, total4);
}